// Round 10
// baseline (353.518 us; speedup 1.0000x reference)
//
#include <hip/hip_runtime.h>
#include <math.h>

#define N_NODES 100000
#define NFEAT 256
#define D1 64          // HEADS*NHID
#define HEADS 8
#define NHID 8
#define NCLASS 32
#define NUM_EDGES 1600000
#define E_TOT 1700000  // + self loops
#define NEG_SLOPE 0.2f

// dst-bucketing: 256 nodes per bucket; CSR stored bucket-strided (no compaction)
#define BSHIFT 8
#define NBUCK 391            // ceil(100000/256)
#define BCAP 5120            // mean edges/bucket 4352, std ~66; +11.6 sigma headroom
#define BIN_EPB 4096
#define BIN_EPT 16

// LESSON (r4): wave-per-node x 25k waves >> block-per-bucket (TLP hides gather latency).
// LESSON (r9): gather MLP fix (edge slots + vector loads + pipeline) 76->63us.
// LESSON (r10-r13): gemm1 — source-level pipelining only sticks when __syncthreads()
// sits between load-issue and use; LDS double-buffer + one barrier/chunk WORKED.
// LESSON (r14/r16): 8-slot uint4 gathers + 2-deep pipeline: gather1 out of top-5 (<60us).
// LESSON (r16): fused layer2 into gather1 / logsoftmax into gather2 (7->5 dispatches).
// LESSON (r17): expm1f = ~30-instr libm expansion; serialized per-wave it tripled the
// epilogue. fast_elu (__expf-1) recovered 96->87us (VALU 89->67%).
// LESSON (r19): remaining epilogue cost = 32 scalar global W2 loads + SERIAL 32-fmaf
// chain + 10-shfl logit tree. Fix: W2 staged in LDS (8KB, 2-way-free banks), 4 partial
// accumulators (chain 32->8), ts/td split across wave halves (one 5-level tree).

// ---- workspace layout (float offsets); h1/h2 are PACKED BF16 (uint = 2 ch) ----
#define OFF_H1    0            // h1b: 3.2M uints
#define OFF_H2    6400000      // h2b: 1.6M uints (old out1 region; h1b still live in gather1)
#define OFF_ALS1  12800000
#define OFF_ALD1  13600000
#define OFF_ALS2  14400000
#define OFF_ALD2  14500000
#define OFF_BCUR  14600000     // 391 ints (pad to 1024)
#define OFF_ROWP  14601024
#define OFF_CNT   14701024
#define OFF_BIN   14801024     // 391*5120 ints (packed dl<<20|src)
#define OFF_CSR   16802944     // 391*5120 ints (dst-sorted src)

typedef __attribute__((ext_vector_type(8))) short bf16x8;
typedef __attribute__((ext_vector_type(4))) float f32x4;

__device__ __forceinline__ float lrelu(float x) { return x >= 0.f ? x : NEG_SLOPE * x; }
__device__ __forceinline__ float fast_elu(float x) { return x > 0.f ? x : __expf(x) - 1.f; }

__device__ __forceinline__ unsigned f32_to_bf16_rne(float f) {
    unsigned u = __float_as_uint(f);
    return (u + 0x7fffu + ((u >> 16) & 1u)) >> 16;
}
__device__ __forceinline__ unsigned pack_bf16x2(float lo, float hi) {
    return f32_to_bf16_rne(lo) | (f32_to_bf16_rne(hi) << 16);
}
__device__ __forceinline__ float2 unpack_bf16x2(unsigned v) {
    return make_float2(__uint_as_float(v << 16), __uint_as_float(v & 0xffff0000u));
}

__device__ __forceinline__ void edge_src_dst(const int* __restrict__ ei, int e, int& src, int& dst) {
    if (e < NUM_EDGES) { src = ei[e]; dst = ei[NUM_EDGES + e]; }
    else { src = e - NUM_EDGES; dst = e - NUM_EDGES; }
}

// ---------------- K1: h1 = x @ W1 via MFMA 16x16x32 bf16; fused logit dots ----------------
// Block: 64 rows x 64 cols, 4 waves; wave w = col-tile (cols w*16..+15 = heads 2w,2w+1).
// Fragment maps (HW-verified in guide): A[m=lane&15][k=quad*8+j], B[k=quad*8+j][n=lane&15],
// C/D col=lane&15, row=quad*4+reg.
// 2-phase pipeline: prefetch chunk kb+1 (regs) -> MFMA chunk kb (LDS buf[cur]) ->
// pack+write buf[nxt] -> ONE barrier. Barriers pin the issue order (r12 lesson).
__global__ __launch_bounds__(256) void gemm1_kernel(const float* __restrict__ x,
                                                    const float* __restrict__ W1,
                                                    const float* __restrict__ a_src,
                                                    const float* __restrict__ a_dst,
                                                    ushort* __restrict__ h1u,
                                                    float* __restrict__ als,
                                                    float* __restrict__ ald) {
    __shared__ unsigned xbf[2][64 * 20];   // double buffer: 64 rows x 32 bf16, stride 20 uints
    const int tid = threadIdx.x;
    const int wv = tid >> 6;            // wave = col-tile
    const int l = tid & 63;
    const int lm = l & 15;
    const int quad = l >> 4;
    const int r0 = blockIdx.x * 64;

    // B-fragments: this wave's 16-col slice of W1, all 8 K-chunks, in registers (32 VGPRs)
    bf16x8 bfrag[8];
#pragma unroll
    for (int kb = 0; kb < 8; kb++)
#pragma unroll
        for (int j = 0; j < 8; j++) {
            const int k = kb * 32 + quad * 8 + j;
            bfrag[kb][j] = (short)f32_to_bf16_rne(W1[k * D1 + wv * 16 + lm]);
        }

    f32x4 acc[4];
#pragma unroll
    for (int s = 0; s < 4; s++) acc[s] = (f32x4)(0.f);

    const int sr = tid >> 2;            // staging: row 0..63
    const int sk = (tid & 3) * 8;       // k-offset within 32-chunk
    const bool rok = (r0 + sr) < N_NODES;
    const float* xrow = &x[(size_t)(r0 + sr) * NFEAT];
    const int swrd = sr * 20 + (tid & 3) * 4;   // LDS write word offset

    // prologue: load + pack + write chunk 0 into buf 0
    {
        uint4 pv = make_uint4(0, 0, 0, 0);
        if (rok) {
            const float4 va = *(const float4*)&xrow[sk];
            const float4 vb = *(const float4*)&xrow[sk + 4];
            pv.x = pack_bf16x2(va.x, va.y);
            pv.y = pack_bf16x2(va.z, va.w);
            pv.z = pack_bf16x2(vb.x, vb.y);
            pv.w = pack_bf16x2(vb.z, vb.w);
        }
        *(uint4*)&xbf[0][swrd] = pv;
    }
    __syncthreads();

#pragma unroll
    for (int kb = 0; kb < 8; kb++) {
        const int cur = kb & 1;
        const int nxt = cur ^ 1;
        // issue next chunk's global loads (in flight during the MFMA phase below;
        // the barrier between issue and use pins this order against the scheduler)
        float4 na = make_float4(0.f, 0.f, 0.f, 0.f);
        float4 nb = make_float4(0.f, 0.f, 0.f, 0.f);
        if (kb < 7 && rok) {
            na = *(const float4*)&xrow[(kb + 1) * 32 + sk];
            nb = *(const float4*)&xrow[(kb + 1) * 32 + sk + 4];
        }
        // MFMA phase: consume buf[cur]
#pragma unroll
        for (int s = 0; s < 4; s++) {
            const uint4 u = *(const uint4*)&xbf[cur][(s * 16 + lm) * 20 + quad * 4];
            const bf16x8 af = *(const bf16x8*)&u;
            acc[s] = __builtin_amdgcn_mfma_f32_16x16x32_bf16(af, bfrag[kb], acc[s], 0, 0, 0);
        }
        // pack + write next chunk into the other buffer (no reader conflict), one barrier
        if (kb < 7) {
            uint4 pv;
            pv.x = pack_bf16x2(na.x, na.y);
            pv.y = pack_bf16x2(na.z, na.w);
            pv.z = pack_bf16x2(nb.x, nb.y);
            pv.w = pack_bf16x2(nb.z, nb.w);
            *(uint4*)&xbf[nxt][swrd] = pv;
            __syncthreads();
        }
    }

    // epilogue: bf16 h1 stores + f32 logit dots (shfl over 8-lane head groups)
    const int head = wv * 2 + (lm >> 3);
    const int jc = l & 7;
    const float asl = a_src[head * NHID + jc];
    const float adl = a_dst[head * NHID + jc];
    const int col = wv * 16 + lm;
#pragma unroll
    for (int s = 0; s < 4; s++) {
#pragma unroll
        for (int r = 0; r < 4; r++) {
            const int row = r0 + s * 16 + quad * 4 + r;
            const float v = acc[s][r];
            float ps = v * asl, pd = v * adl;
            ps += __shfl_xor(ps, 1, 64); pd += __shfl_xor(pd, 1, 64);
            ps += __shfl_xor(ps, 2, 64); pd += __shfl_xor(pd, 2, 64);
            ps += __shfl_xor(ps, 4, 64); pd += __shfl_xor(pd, 4, 64);
            if (row < N_NODES) {
                h1u[(size_t)row * D1 + col] = (ushort)f32_to_bf16_rne(v);
                if (jc == 0) { als[row * HEADS + head] = ps; ald[row * HEADS + head] = pd; }
            }
        }
    }
}

// ---------------- K2: bin edges by dst bucket (LDS hist + chunk reservation) ----------------
// packed entry: (dst&255)<<20 | src   (src < 2^17)
__global__ __launch_bounds__(256) void bin_kernel(const int* __restrict__ ei,
                                                  int* __restrict__ bcur,
                                                  int* __restrict__ bin) {
    __shared__ int lcnt[NBUCK];
    __shared__ int lbase[NBUCK];
    const int tid = threadIdx.x;
    for (int b = tid; b < NBUCK; b += 256) lcnt[b] = 0;
    __syncthreads();
    const int e0 = blockIdx.x * BIN_EPB;
    int pk[BIN_EPT], bk[BIN_EPT], loff[BIN_EPT];
#pragma unroll
    for (int i = 0; i < BIN_EPT; i++) {
        const int e = e0 + i * 256 + tid;
        if (e < E_TOT) {
            int src, dst; edge_src_dst(ei, e, src, dst);
            bk[i] = dst >> BSHIFT;
            pk[i] = ((dst & 255) << 20) | src;
            loff[i] = atomicAdd(&lcnt[bk[i]], 1);
        } else bk[i] = -1;
    }
    __syncthreads();
    for (int b = tid; b < NBUCK; b += 256) {
        const int c = lcnt[b];
        lbase[b] = c ? atomicAdd(&bcur[b], c) : 0;
    }
    __syncthreads();
#pragma unroll
    for (int i = 0; i < BIN_EPT; i++) {
        if (bk[i] >= 0)
            bin[(size_t)bk[i] * BCAP + lbase[bk[i]] + loff[i]] = pk[i];
    }
}

// ---------------- K3: per-bucket LDS counting sort -> dst-sorted CSR ----------------
__global__ __launch_bounds__(256) void bsort_kernel(const int* __restrict__ bcur,
                                                    const int* __restrict__ bin,
                                                    int* __restrict__ csr,
                                                    int* __restrict__ row_ptr,
                                                    int* __restrict__ cnt) {
    __shared__ int hcnt[256];
    __shared__ int hpre[256];
    __shared__ int cur[256];
    __shared__ int ssrc[BCAP];   // 20 KB
    const int tid = threadIdx.x;
    const int bkt = blockIdx.x;
    const int cntb = bcur[bkt];
    const int base = bkt * BCAP;
    hcnt[tid] = 0;
    __syncthreads();
    for (int i = tid; i < cntb; i += 256)
        atomicAdd(&hcnt[bin[base + i] >> 20], 1);
    __syncthreads();
    const int myc = hcnt[tid];
    hpre[tid] = myc;
    __syncthreads();
    for (int off = 1; off < 256; off <<= 1) {
        const int t = (tid >= off) ? hpre[tid - off] : 0;
        __syncthreads();
        hpre[tid] += t;
        __syncthreads();
    }
    const int exc = hpre[tid] - myc;
    cur[tid] = exc;
    __syncthreads();
    for (int i = tid; i < cntb; i += 256) {
        const int v = bin[base + i];
        const int pos = atomicAdd(&cur[v >> 20], 1);
        ssrc[pos] = v & 0xFFFFF;
    }
    __syncthreads();
    for (int i = tid; i < cntb; i += 256) csr[base + i] = ssrc[i];
    const int n = (bkt << BSHIFT) + tid;
    if (n < N_NODES) { row_ptr[n] = base + exc; cnt[n] = myc; }
}

// ---------------- K4: gather layer 1 + FUSED layer2 ----------------
// Gather: wave/node, 8 lanes x uint4 (head octet), 8 edge slots, 2-deep value pipeline.
// Epilogue: z = fast_elu(out1+b1) staged in LDS -> y = z @ W2 across 64 lanes with
// W2 in LDS (no VMEM in the dot) + 4 partial accumulators (short dep chain) ->
// half-split logit tree -> h2 packed bf16. out1 never touches HBM.
__global__ __launch_bounds__(256) void gather1_kernel(const int* __restrict__ row_ptr,
                                                      const int* __restrict__ cnt,
                                                      const int* __restrict__ csr_src,
                                                      const unsigned* __restrict__ h1b,
                                                      const float* __restrict__ als,
                                                      const float* __restrict__ ald,
                                                      const float* __restrict__ b1,
                                                      const float* __restrict__ W2,
                                                      const float* __restrict__ a_src2,
                                                      const float* __restrict__ a_dst2,
                                                      unsigned* __restrict__ h2b,
                                                      float* __restrict__ als2,
                                                      float* __restrict__ ald2) {
    __shared__ float zbuf[4][64];                // per-wave z row (1 KB)
    __shared__ float w2l[D1 * NCLASS];           // 8 KB, staged once per block
    const int tid = threadIdx.x;
    const int wv = tid >> 6;
    const int n = blockIdx.x * 4 + wv;           // grid == N_NODES/4 exactly
    const int l = tid & 63;
    const int q = l >> 3;                        // edge slot 0..7
    const int h = l & 7;                         // head = channel octet 8h..8h+7
    for (int idx = tid; idx < D1 * NCLASS; idx += 256) w2l[idx] = W2[idx];
    const int start = row_ptr[n];
    const int deg = cnt[n];
    const float aldn = ald[n * HEADS + h];
    float a0 = 0.f, a1 = 0.f, a2 = 0.f, a3 = 0.f;
    float a4 = 0.f, a5 = 0.f, a6 = 0.f, a7 = 0.f, wsum = 0.f;

    int i = q;
    float e0 = 0.f, e1 = 0.f;
    uint4 u0 = make_uint4(0u, 0u, 0u, 0u);
    uint4 u1 = make_uint4(0u, 0u, 0u, 0u);
    int s2 = 0;
    if (i < deg) {
        const int s0 = csr_src[start + i];
        e0 = als[s0 * HEADS + h];
        u0 = *(const uint4*)&h1b[(size_t)s0 * 32 + h * 4];
    }
    if (i + 8 < deg) {
        const int s1 = csr_src[start + i + 8];
        e1 = als[s1 * HEADS + h];
        u1 = *(const uint4*)&h1b[(size_t)s1 * 32 + h * 4];
    }
    if (i + 16 < deg) s2 = csr_src[start + i + 16];

    for (; i < deg; i += 8) {
        int s3 = 0;
        if (i + 24 < deg) s3 = csr_src[start + i + 24];
        float e2 = 0.f;
        uint4 u2 = make_uint4(0u, 0u, 0u, 0u);
        if (i + 16 < deg) {
            e2 = als[s2 * HEADS + h];
            u2 = *(const uint4*)&h1b[(size_t)s2 * 32 + h * 4];
        }
        const float w = __expf(lrelu(e0 + aldn));
        const float2 p0 = unpack_bf16x2(u0.x);
        const float2 p1 = unpack_bf16x2(u0.y);
        const float2 p2 = unpack_bf16x2(u0.z);
        const float2 p3 = unpack_bf16x2(u0.w);
        a0 = fmaf(p0.x, w, a0); a1 = fmaf(p0.y, w, a1);
        a2 = fmaf(p1.x, w, a2); a3 = fmaf(p1.y, w, a3);
        a4 = fmaf(p2.x, w, a4); a5 = fmaf(p2.y, w, a5);
        a6 = fmaf(p3.x, w, a6); a7 = fmaf(p3.y, w, a7);
        wsum += w;
        e0 = e1; u0 = u1; e1 = e2; u1 = u2; s2 = s3;
    }

    // reduce across the 8 slots (8-lane groups)
    a0 += __shfl_down(a0, 32, 64); a1 += __shfl_down(a1, 32, 64);
    a2 += __shfl_down(a2, 32, 64); a3 += __shfl_down(a3, 32, 64);
    a4 += __shfl_down(a4, 32, 64); a5 += __shfl_down(a5, 32, 64);
    a6 += __shfl_down(a6, 32, 64); a7 += __shfl_down(a7, 32, 64);
    wsum += __shfl_down(wsum, 32, 64);
    a0 += __shfl_down(a0, 16, 64); a1 += __shfl_down(a1, 16, 64);
    a2 += __shfl_down(a2, 16, 64); a3 += __shfl_down(a3, 16, 64);
    a4 += __shfl_down(a4, 16, 64); a5 += __shfl_down(a5, 16, 64);
    a6 += __shfl_down(a6, 16, 64); a7 += __shfl_down(a7, 16, 64);
    wsum += __shfl_down(wsum, 16, 64);
    a0 += __shfl_down(a0, 8, 64); a1 += __shfl_down(a1, 8, 64);
    a2 += __shfl_down(a2, 8, 64); a3 += __shfl_down(a3, 8, 64);
    a4 += __shfl_down(a4, 8, 64); a5 += __shfl_down(a5, 8, 64);
    a6 += __shfl_down(a6, 8, 64); a7 += __shfl_down(a7, 8, 64);
    wsum += __shfl_down(wsum, 8, 64);

    // ---- fused layer2 (fast_elu: single v_exp each, r17 lesson) ----
    if (l < 8) {                                  // lane l holds channels 8l..8l+7
        const float inv = 1.f / (wsum + 1e-16f);
        const float4 b1a = *(const float4*)&b1[l * 8];
        const float4 b1b = *(const float4*)&b1[l * 8 + 4];
        const float z0 = fast_elu(a0 * inv + b1a.x);
        const float z1 = fast_elu(a1 * inv + b1a.y);
        const float z2 = fast_elu(a2 * inv + b1a.z);
        const float z3 = fast_elu(a3 * inv + b1a.w);
        const float z4 = fast_elu(a4 * inv + b1b.x);
        const float z5 = fast_elu(a5 * inv + b1b.y);
        const float z6 = fast_elu(a6 * inv + b1b.z);
        const float z7 = fast_elu(a7 * inv + b1b.w);
        *(float4*)&zbuf[wv][l * 8]     = make_float4(z0, z1, z2, z3);
        *(float4*)&zbuf[wv][l * 8 + 4] = make_float4(z4, z5, z6, z7);
    }
    __syncthreads();   // also covers the one-time w2l staging (first barrier in kernel)

    // y[c] = sum_k z[k] * W2[k][c]; W2 from LDS (2-way bank alias across halves = free),
    // 4 partial accumulators to break the serial fmaf chain.
    const int c = l & 31;                         // output class
    const int kh = l >> 5;                        // k-half
    float y0 = 0.f, y1 = 0.f, y2 = 0.f, y3 = 0.f;
    const float* wl = &w2l[kh * 32 * NCLASS + c];
#pragma unroll
    for (int j4 = 0; j4 < 2; j4++) {
        const int k0 = j4 * 16;
        const float4 za = *(const float4*)&zbuf[wv][kh * 32 + k0];
        const float4 zb = *(const float4*)&zbuf[wv][kh * 32 + k0 + 4];
        const float4 zc = *(const float4*)&zbuf[wv][kh * 32 + k0 + 8];
        const float4 zd = *(const float4*)&zbuf[wv][kh * 32 + k0 + 12];
        y0 = fmaf(za.x, wl[(k0 + 0) * NCLASS], y0);
        y1 = fmaf(za.y, wl[(k0 + 1) * NCLASS], y1);
        y2 = fmaf(za.z, wl[(k0 + 2) * NCLASS], y2);
        y3 = fmaf(za.w, wl[(k0 + 3) * NCLASS], y3);
        y0 = fmaf(zb.x, wl[(k0 + 4) * NCLASS], y0);
        y1 = fmaf(zb.y, wl[(k0 + 5) * NCLASS], y1);
        y2 = fmaf(zb.z, wl[(k0 + 6) * NCLASS], y2);
        y3 = fmaf(zb.w, wl[(k0 + 7) * NCLASS], y3);
        y0 = fmaf(zc.x, wl[(k0 + 8) * NCLASS], y0);
        y1 = fmaf(zc.y, wl[(k0 + 9) * NCLASS], y1);
        y2 = fmaf(zc.z, wl[(k0 + 10) * NCLASS], y2);
        y3 = fmaf(zc.w, wl[(k0 + 11) * NCLASS], y3);
        y0 = fmaf(zd.x, wl[(k0 + 12) * NCLASS], y0);
        y1 = fmaf(zd.y, wl[(k0 + 13) * NCLASS], y1);
        y2 = fmaf(zd.z, wl[(k0 + 14) * NCLASS], y2);
        y3 = fmaf(zd.w, wl[(k0 + 15) * NCLASS], y3);
    }
    float y = (y0 + y1) + (y2 + y3);
    y += __shfl_xor(y, 32, 64);                   // full y[c] on all lanes

    // layer-2 logit dots: lower half reduces y*a_src2, upper half y*a_dst2
    // (one 5-level tree within each 32-lane half; xor<32 stays in-half)
    float part = y * ((l < 32) ? a_src2[c] : a_dst2[c]);
    part += __shfl_xor(part, 1, 64);
    part += __shfl_xor(part, 2, 64);
    part += __shfl_xor(part, 4, 64);
    part += __shfl_xor(part, 8, 64);
    part += __shfl_xor(part, 16, 64);
    const float tdv = __shfl(part, 32, 64);       // td (upper-half sum)
    if (l == 0) { als2[n] = part; ald2[n] = tdv; }

    // pack h2 bf16: even lanes of lower half pack (y[c], y[c+1]) -> word c>>1
    const unsigned pw = pack_bf16x2(y, __shfl_down(y, 1, 64));
    if (l < 32 && (l & 1) == 0) h2b[(size_t)n * 16 + (l >> 1)] = pw;
}

// ---------------- K5: gather layer 2 + FUSED log_softmax ----------------
// Gather: wave/node, 4 lanes x uint4 (8ch), 16 edge slots, 2-deep pipeline.
// Epilogue: +b2, shfl-max, shfl-sum-exp over the 4-lane group, write final out.
__global__ __launch_bounds__(256) void gather2_kernel(const int* __restrict__ row_ptr,
                                                      const int* __restrict__ cnt,
                                                      const int* __restrict__ csr_src,
                                                      const unsigned* __restrict__ h2b,
                                                      const float* __restrict__ als2,
                                                      const float* __restrict__ ald2,
                                                      const float* __restrict__ b2,
                                                      float* __restrict__ out) {
    const int tid = threadIdx.x;
    const int n = blockIdx.x * 4 + (tid >> 6);   // grid == N_NODES/4 exactly
    const int l = tid & 63;
    const int q = l >> 2;                        // edge slot 0..15
    const int c = l & 3;                         // channel octet: ch 8c..8c+7
    const int start = row_ptr[n];
    const int deg = cnt[n];
    const float aldn = ald2[n];
    float a0 = 0.f, a1 = 0.f, a2 = 0.f, a3 = 0.f;
    float a4 = 0.f, a5 = 0.f, a6 = 0.f, a7 = 0.f, wsum = 0.f;

    int i = q;
    float e0 = 0.f, e1 = 0.f;
    uint4 u0 = make_uint4(0u, 0u, 0u, 0u);
    uint4 u1 = make_uint4(0u, 0u, 0u, 0u);
    int s2 = 0;
    if (i < deg) {
        const int s0 = csr_src[start + i];
        e0 = als2[s0];
        u0 = *(const uint4*)&h2b[(size_t)s0 * 16 + c * 4];
    }
    if (i + 16 < deg) {
        const int s1 = csr_src[start + i + 16];
        e1 = als2[s1];
        u1 = *(const uint4*)&h2b[(size_t)s1 * 16 + c * 4];
    }
    if (i + 32 < deg) s2 = csr_src[start + i + 32];

    for (; i < deg; i += 16) {
        int s3 = 0;
        if (i + 48 < deg) s3 = csr_src[start + i + 48];
        float e2 = 0.f;
        uint4 u2 = make_uint4(0u, 0u, 0u, 0u);
        if (i + 32 < deg) {
            e2 = als2[s2];
            u2 = *(const uint4*)&h2b[(size_t)s2 * 16 + c * 4];
        }
        const float w = __expf(lrelu(e0 + aldn));
        const float2 p0 = unpack_bf16x2(u0.x);
        const float2 p1 = unpack_bf16x2(u0.y);
        const float2 p2 = unpack_bf16x2(u0.z);
        const float2 p3 = unpack_bf16x2(u0.w);
        a0 = fmaf(p0.x, w, a0); a1 = fmaf(p0.y, w, a1);
        a2 = fmaf(p1.x, w, a2); a3 = fmaf(p1.y, w, a3);
        a4 = fmaf(p2.x, w, a4); a5 = fmaf(p2.y, w, a5);
        a6 = fmaf(p3.x, w, a6); a7 = fmaf(p3.y, w, a7);
        wsum += w;
        e0 = e1; u0 = u1; e1 = e2; u1 = u2; s2 = s3;
    }

    // reduce across the 16 slots (4-lane groups)
    a0 += __shfl_down(a0, 32, 64); a1 += __shfl_down(a1, 32, 64);
    a2 += __shfl_down(a2, 32, 64); a3 += __shfl_down(a3, 32, 64);
    a4 += __shfl_down(a4, 32, 64); a5 += __shfl_down(a5, 32, 64);
    a6 += __shfl_down(a6, 32, 64); a7 += __shfl_down(a7, 32, 64);
    wsum += __shfl_down(wsum, 32, 64);
    a0 += __shfl_down(a0, 16, 64); a1 += __shfl_down(a1, 16, 64);
    a2 += __shfl_down(a2, 16, 64); a3 += __shfl_down(a3, 16, 64);
    a4 += __shfl_down(a4, 16, 64); a5 += __shfl_down(a5, 16, 64);
    a6 += __shfl_down(a6, 16, 64); a7 += __shfl_down(a7, 16, 64);
    wsum += __shfl_down(wsum, 16, 64);
    a0 += __shfl_down(a0, 8, 64); a1 += __shfl_down(a1, 8, 64);
    a2 += __shfl_down(a2, 8, 64); a3 += __shfl_down(a3, 8, 64);
    a4 += __shfl_down(a4, 8, 64); a5 += __shfl_down(a5, 8, 64);
    a6 += __shfl_down(a6, 8, 64); a7 += __shfl_down(a7, 8, 64);
    wsum += __shfl_down(wsum, 8, 64);
    a0 += __shfl_down(a0, 4, 64); a1 += __shfl_down(a1, 4, 64);
    a2 += __shfl_down(a2, 4, 64); a3 += __shfl_down(a3, 4, 64);
    a4 += __shfl_down(a4, 4, 64); a5 += __shfl_down(a5, 4, 64);
    a6 += __shfl_down(a6, 4, 64); a7 += __shfl_down(a7, 4, 64);
    wsum += __shfl_down(wsum, 4, 64);

    // ---- fused +b2 and log_softmax over the 4-lane group ----
    const float inv = 1.f / (wsum + 1e-16f);
    const float4 b2a = *(const float4*)&b2[c * 8];
    const float4 b2b = *(const float4*)&b2[c * 8 + 4];
    const float v0 = a0 * inv + b2a.x, v1 = a1 * inv + b2a.y;
    const float v2 = a2 * inv + b2a.z, v3 = a3 * inv + b2a.w;
    const float v4 = a4 * inv + b2b.x, v5 = a5 * inv + b2b.y;
    const float v6 = a6 * inv + b2b.z, v7 = a7 * inv + b2b.w;
    float mx = fmaxf(fmaxf(fmaxf(v0, v1), fmaxf(v2, v3)),
                     fmaxf(fmaxf(v4, v5), fmaxf(v6, v7)));
    mx = fmaxf(mx, __shfl_xor(mx, 1, 64));
    mx = fmaxf(mx, __shfl_xor(mx, 2, 64));
    float s = __expf(v0 - mx) + __expf(v1 - mx) + __expf(v2 - mx) + __expf(v3 - mx)
            + __expf(v4 - mx) + __expf(v5 - mx) + __expf(v6 - mx) + __expf(v7 - mx);
    s += __shfl_xor(s, 1, 64);
    s += __shfl_xor(s, 2, 64);
    const float lse = mx + logf(s);
    if (l < 4) {
        float* op = &out[(size_t)n * NCLASS + c * 8];
        *(float4*)&op[0] = make_float4(v0 - lse, v1 - lse, v2 - lse, v3 - lse);
        *(float4*)&op[4] = make_float4(v4 - lse, v5 - lse, v6 - lse, v7 - lse);
    }
}

extern "C" void kernel_launch(void* const* d_in, const int* in_sizes, int n_in,
                              void* d_out, int out_size, void* d_ws, size_t ws_size,
                              hipStream_t stream) {
    const float* x      = (const float*)d_in[0];
    const int*   ei     = (const int*)d_in[1];
    const float* W1     = (const float*)d_in[2];
    const float* a_src1 = (const float*)d_in[3];
    const float* a_dst1 = (const float*)d_in[4];
    const float* b1     = (const float*)d_in[5];
    const float* W2     = (const float*)d_in[6];
    const float* a_src2 = (const float*)d_in[7];
    const float* a_dst2 = (const float*)d_in[8];
    const float* b2     = (const float*)d_in[9];
    float* out = (float*)d_out;
    float* ws  = (float*)d_ws;

    ushort* h1u     = (ushort*)(ws + OFF_H1);
    unsigned* h1b   = (unsigned*)(ws + OFF_H1);
    unsigned* h2b   = (unsigned*)(ws + OFF_H2);          // distinct region: h1b still live in gather1
    float* als1     = ws + OFF_ALS1;
    float* ald1     = ws + OFF_ALD1;
    float* als2     = ws + OFF_ALS2;
    float* ald2     = ws + OFF_ALD2;
    int*   bcur     = (int*)(ws + OFF_BCUR);
    int*   row_ptr  = (int*)(ws + OFF_ROWP);
    int*   cnt      = (int*)(ws + OFF_CNT);
    int*   bin      = (int*)(ws + OFF_BIN);
    int*   csr      = (int*)(ws + OFF_CSR);

    hipMemsetAsync(bcur, 0, NBUCK * sizeof(int), stream);

    gemm1_kernel<<<(N_NODES + 63) / 64, 256, 0, stream>>>(x, W1, a_src1, a_dst1, h1u, als1, ald1);
    bin_kernel<<<(E_TOT + BIN_EPB - 1) / BIN_EPB, 256, 0, stream>>>(ei, bcur, bin);
    bsort_kernel<<<NBUCK, 256, 0, stream>>>(bcur, bin, csr, row_ptr, cnt);
    gather1_kernel<<<N_NODES / 4, 256, 0, stream>>>(row_ptr, cnt, csr, h1b, als1, ald1,
                                                    b1, W2, a_src2, a_dst2, h2b, als2, ald2);
    gather2_kernel<<<N_NODES / 4, 256, 0, stream>>>(row_ptr, cnt, csr, h2b, als2, ald2, b2, out);
}

// Round 11
// 337.008 us; speedup vs baseline: 1.0490x; 1.0490x over previous
//
#include <hip/hip_runtime.h>
#include <math.h>

#define N_NODES 100000
#define NFEAT 256
#define D1 64          // HEADS*NHID
#define HEADS 8
#define NHID 8
#define NCLASS 32
#define NUM_EDGES 1600000
#define E_TOT 1700000  // + self loops
#define NEG_SLOPE 0.2f

// dst-bucketing: 256 nodes per bucket; CSR stored bucket-strided (no compaction)
#define BSHIFT 8
#define NBUCK 391            // ceil(100000/256)
#define BCAP 5120            // mean edges/bucket 4352, std ~66; +11.6 sigma headroom
#define BIN_EPB 4096
#define BIN_EPT 16

// LESSON (r4): wave-per-node x 25k waves >> block-per-bucket (TLP hides gather latency).
// LESSON (r9): gather MLP fix (edge slots + vector loads + pipeline) 76->63us.
// LESSON (r10-r13): gemm1 — source-level pipelining only sticks when __syncthreads()
// sits between load-issue and use; LDS double-buffer + one barrier/chunk WORKED.
// LESSON (r14/r16): 8-slot uint4 gathers + 2-deep pipeline: gather1 out of top-5 (<60us).
// LESSON (r16): fused layer2 into gather1 / logsoftmax into gather2 (7->5 dispatches).
// LESSON (r17): expm1f = ~30-instr libm expansion; fast_elu recovered 96->87us.
// LESSON (r19/r20): epilogue cost is NOT dot throughput (LDS-W2 + partials = null).
// HBM BW fell 2.9->1.8 TB/s with same bytes: device-wide loop/epilogue phase alternation
// — __syncthreads() convoyed the 4 waves + drained vmcnt, so no loads in flight during
// epilogues. FIX: barrier-FREE epilogue. zbuf is per-wave; DS ops within one wave are
// in-order at the LDS, so wave_barrier (compiler fence) suffices. W2 direct from global.

// ---- workspace layout (float offsets); h1/h2 are PACKED BF16 (uint = 2 ch) ----
#define OFF_H1    0            // h1b: 3.2M uints
#define OFF_H2    6400000      // h2b: 1.6M uints (old out1 region; h1b still live in gather1)
#define OFF_ALS1  12800000
#define OFF_ALD1  13600000
#define OFF_ALS2  14400000
#define OFF_ALD2  14500000
#define OFF_BCUR  14600000     // 391 ints (pad to 1024)
#define OFF_ROWP  14601024
#define OFF_CNT   14701024
#define OFF_BIN   14801024     // 391*5120 ints (packed dl<<20|src)
#define OFF_CSR   16802944     // 391*5120 ints (dst-sorted src)

typedef __attribute__((ext_vector_type(8))) short bf16x8;
typedef __attribute__((ext_vector_type(4))) float f32x4;

__device__ __forceinline__ float lrelu(float x) { return x >= 0.f ? x : NEG_SLOPE * x; }
__device__ __forceinline__ float fast_elu(float x) { return x > 0.f ? x : __expf(x) - 1.f; }

__device__ __forceinline__ unsigned f32_to_bf16_rne(float f) {
    unsigned u = __float_as_uint(f);
    return (u + 0x7fffu + ((u >> 16) & 1u)) >> 16;
}
__device__ __forceinline__ unsigned pack_bf16x2(float lo, float hi) {
    return f32_to_bf16_rne(lo) | (f32_to_bf16_rne(hi) << 16);
}
__device__ __forceinline__ float2 unpack_bf16x2(unsigned v) {
    return make_float2(__uint_as_float(v << 16), __uint_as_float(v & 0xffff0000u));
}

__device__ __forceinline__ void edge_src_dst(const int* __restrict__ ei, int e, int& src, int& dst) {
    if (e < NUM_EDGES) { src = ei[e]; dst = ei[NUM_EDGES + e]; }
    else { src = e - NUM_EDGES; dst = e - NUM_EDGES; }
}

// ---------------- K1: h1 = x @ W1 via MFMA 16x16x32 bf16; fused logit dots ----------------
// Block: 64 rows x 64 cols, 4 waves; wave w = col-tile (cols w*16..+15 = heads 2w,2w+1).
// Fragment maps (HW-verified in guide): A[m=lane&15][k=quad*8+j], B[k=quad*8+j][n=lane&15],
// C/D col=lane&15, row=quad*4+reg.
// 2-phase pipeline: prefetch chunk kb+1 (regs) -> MFMA chunk kb (LDS buf[cur]) ->
// pack+write buf[nxt] -> ONE barrier. Barriers pin the issue order (r12 lesson).
__global__ __launch_bounds__(256) void gemm1_kernel(const float* __restrict__ x,
                                                    const float* __restrict__ W1,
                                                    const float* __restrict__ a_src,
                                                    const float* __restrict__ a_dst,
                                                    ushort* __restrict__ h1u,
                                                    float* __restrict__ als,
                                                    float* __restrict__ ald) {
    __shared__ unsigned xbf[2][64 * 20];   // double buffer: 64 rows x 32 bf16, stride 20 uints
    const int tid = threadIdx.x;
    const int wv = tid >> 6;            // wave = col-tile
    const int l = tid & 63;
    const int lm = l & 15;
    const int quad = l >> 4;
    const int r0 = blockIdx.x * 64;

    // B-fragments: this wave's 16-col slice of W1, all 8 K-chunks, in registers (32 VGPRs)
    bf16x8 bfrag[8];
#pragma unroll
    for (int kb = 0; kb < 8; kb++)
#pragma unroll
        for (int j = 0; j < 8; j++) {
            const int k = kb * 32 + quad * 8 + j;
            bfrag[kb][j] = (short)f32_to_bf16_rne(W1[k * D1 + wv * 16 + lm]);
        }

    f32x4 acc[4];
#pragma unroll
    for (int s = 0; s < 4; s++) acc[s] = (f32x4)(0.f);

    const int sr = tid >> 2;            // staging: row 0..63
    const int sk = (tid & 3) * 8;       // k-offset within 32-chunk
    const bool rok = (r0 + sr) < N_NODES;
    const float* xrow = &x[(size_t)(r0 + sr) * NFEAT];
    const int swrd = sr * 20 + (tid & 3) * 4;   // LDS write word offset

    // prologue: load + pack + write chunk 0 into buf 0
    {
        uint4 pv = make_uint4(0, 0, 0, 0);
        if (rok) {
            const float4 va = *(const float4*)&xrow[sk];
            const float4 vb = *(const float4*)&xrow[sk + 4];
            pv.x = pack_bf16x2(va.x, va.y);
            pv.y = pack_bf16x2(va.z, va.w);
            pv.z = pack_bf16x2(vb.x, vb.y);
            pv.w = pack_bf16x2(vb.z, vb.w);
        }
        *(uint4*)&xbf[0][swrd] = pv;
    }
    __syncthreads();

#pragma unroll
    for (int kb = 0; kb < 8; kb++) {
        const int cur = kb & 1;
        const int nxt = cur ^ 1;
        // issue next chunk's global loads (in flight during the MFMA phase below;
        // the barrier between issue and use pins this order against the scheduler)
        float4 na = make_float4(0.f, 0.f, 0.f, 0.f);
        float4 nb = make_float4(0.f, 0.f, 0.f, 0.f);
        if (kb < 7 && rok) {
            na = *(const float4*)&xrow[(kb + 1) * 32 + sk];
            nb = *(const float4*)&xrow[(kb + 1) * 32 + sk + 4];
        }
        // MFMA phase: consume buf[cur]
#pragma unroll
        for (int s = 0; s < 4; s++) {
            const uint4 u = *(const uint4*)&xbf[cur][(s * 16 + lm) * 20 + quad * 4];
            const bf16x8 af = *(const bf16x8*)&u;
            acc[s] = __builtin_amdgcn_mfma_f32_16x16x32_bf16(af, bfrag[kb], acc[s], 0, 0, 0);
        }
        // pack + write next chunk into the other buffer (no reader conflict), one barrier
        if (kb < 7) {
            uint4 pv;
            pv.x = pack_bf16x2(na.x, na.y);
            pv.y = pack_bf16x2(na.z, na.w);
            pv.z = pack_bf16x2(nb.x, nb.y);
            pv.w = pack_bf16x2(nb.z, nb.w);
            *(uint4*)&xbf[nxt][swrd] = pv;
            __syncthreads();
        }
    }

    // epilogue: bf16 h1 stores + f32 logit dots (shfl over 8-lane head groups)
    const int head = wv * 2 + (lm >> 3);
    const int jc = l & 7;
    const float asl = a_src[head * NHID + jc];
    const float adl = a_dst[head * NHID + jc];
    const int col = wv * 16 + lm;
#pragma unroll
    for (int s = 0; s < 4; s++) {
#pragma unroll
        for (int r = 0; r < 4; r++) {
            const int row = r0 + s * 16 + quad * 4 + r;
            const float v = acc[s][r];
            float ps = v * asl, pd = v * adl;
            ps += __shfl_xor(ps, 1, 64); pd += __shfl_xor(pd, 1, 64);
            ps += __shfl_xor(ps, 2, 64); pd += __shfl_xor(pd, 2, 64);
            ps += __shfl_xor(ps, 4, 64); pd += __shfl_xor(pd, 4, 64);
            if (row < N_NODES) {
                h1u[(size_t)row * D1 + col] = (ushort)f32_to_bf16_rne(v);
                if (jc == 0) { als[row * HEADS + head] = ps; ald[row * HEADS + head] = pd; }
            }
        }
    }
}

// ---------------- K2: bin edges by dst bucket (LDS hist + chunk reservation) ----------------
// packed entry: (dst&255)<<20 | src   (src < 2^17)
__global__ __launch_bounds__(256) void bin_kernel(const int* __restrict__ ei,
                                                  int* __restrict__ bcur,
                                                  int* __restrict__ bin) {
    __shared__ int lcnt[NBUCK];
    __shared__ int lbase[NBUCK];
    const int tid = threadIdx.x;
    for (int b = tid; b < NBUCK; b += 256) lcnt[b] = 0;
    __syncthreads();
    const int e0 = blockIdx.x * BIN_EPB;
    int pk[BIN_EPT], bk[BIN_EPT], loff[BIN_EPT];
#pragma unroll
    for (int i = 0; i < BIN_EPT; i++) {
        const int e = e0 + i * 256 + tid;
        if (e < E_TOT) {
            int src, dst; edge_src_dst(ei, e, src, dst);
            bk[i] = dst >> BSHIFT;
            pk[i] = ((dst & 255) << 20) | src;
            loff[i] = atomicAdd(&lcnt[bk[i]], 1);
        } else bk[i] = -1;
    }
    __syncthreads();
    for (int b = tid; b < NBUCK; b += 256) {
        const int c = lcnt[b];
        lbase[b] = c ? atomicAdd(&bcur[b], c) : 0;
    }
    __syncthreads();
#pragma unroll
    for (int i = 0; i < BIN_EPT; i++) {
        if (bk[i] >= 0)
            bin[(size_t)bk[i] * BCAP + lbase[bk[i]] + loff[i]] = pk[i];
    }
}

// ---------------- K3: per-bucket LDS counting sort -> dst-sorted CSR ----------------
__global__ __launch_bounds__(256) void bsort_kernel(const int* __restrict__ bcur,
                                                    const int* __restrict__ bin,
                                                    int* __restrict__ csr,
                                                    int* __restrict__ row_ptr,
                                                    int* __restrict__ cnt) {
    __shared__ int hcnt[256];
    __shared__ int hpre[256];
    __shared__ int cur[256];
    __shared__ int ssrc[BCAP];   // 20 KB
    const int tid = threadIdx.x;
    const int bkt = blockIdx.x;
    const int cntb = bcur[bkt];
    const int base = bkt * BCAP;
    hcnt[tid] = 0;
    __syncthreads();
    for (int i = tid; i < cntb; i += 256)
        atomicAdd(&hcnt[bin[base + i] >> 20], 1);
    __syncthreads();
    const int myc = hcnt[tid];
    hpre[tid] = myc;
    __syncthreads();
    for (int off = 1; off < 256; off <<= 1) {
        const int t = (tid >= off) ? hpre[tid - off] : 0;
        __syncthreads();
        hpre[tid] += t;
        __syncthreads();
    }
    const int exc = hpre[tid] - myc;
    cur[tid] = exc;
    __syncthreads();
    for (int i = tid; i < cntb; i += 256) {
        const int v = bin[base + i];
        const int pos = atomicAdd(&cur[v >> 20], 1);
        ssrc[pos] = v & 0xFFFFF;
    }
    __syncthreads();
    for (int i = tid; i < cntb; i += 256) csr[base + i] = ssrc[i];
    const int n = (bkt << BSHIFT) + tid;
    if (n < N_NODES) { row_ptr[n] = base + exc; cnt[n] = myc; }
}

// ---------------- K4: gather layer 1 + FUSED layer2 (barrier-free epilogue) ----------------
// Gather: wave/node, 8 lanes x uint4 (head octet), 8 edge slots, 2-deep value pipeline.
// Epilogue is WAVE-LOCAL: zbuf[wv] written by lanes 0-7, read by all 64 lanes of the
// SAME wave. DS ops within one wave execute in order at the LDS; wave_barrier + memory
// fence pins compiler ordering. NO __syncthreads -> waves retire independently, loop
// loads from other waves stay in flight during epilogues (r20 lesson).
__global__ __launch_bounds__(256) void gather1_kernel(const int* __restrict__ row_ptr,
                                                      const int* __restrict__ cnt,
                                                      const int* __restrict__ csr_src,
                                                      const unsigned* __restrict__ h1b,
                                                      const float* __restrict__ als,
                                                      const float* __restrict__ ald,
                                                      const float* __restrict__ b1,
                                                      const float* __restrict__ W2,
                                                      const float* __restrict__ a_src2,
                                                      const float* __restrict__ a_dst2,
                                                      unsigned* __restrict__ h2b,
                                                      float* __restrict__ als2,
                                                      float* __restrict__ ald2) {
    __shared__ float zbuf[4][64];                // per-wave z row (1 KB)
    const int tid = threadIdx.x;
    const int wv = tid >> 6;
    const int n = blockIdx.x * 4 + wv;           // grid == N_NODES/4 exactly
    const int l = tid & 63;
    const int q = l >> 3;                        // edge slot 0..7
    const int h = l & 7;                         // head = channel octet 8h..8h+7
    const int start = row_ptr[n];
    const int deg = cnt[n];
    const float aldn = ald[n * HEADS + h];
    float a0 = 0.f, a1 = 0.f, a2 = 0.f, a3 = 0.f;
    float a4 = 0.f, a5 = 0.f, a6 = 0.f, a7 = 0.f, wsum = 0.f;

    int i = q;
    float e0 = 0.f, e1 = 0.f;
    uint4 u0 = make_uint4(0u, 0u, 0u, 0u);
    uint4 u1 = make_uint4(0u, 0u, 0u, 0u);
    int s2 = 0;
    if (i < deg) {
        const int s0 = csr_src[start + i];
        e0 = als[s0 * HEADS + h];
        u0 = *(const uint4*)&h1b[(size_t)s0 * 32 + h * 4];
    }
    if (i + 8 < deg) {
        const int s1 = csr_src[start + i + 8];
        e1 = als[s1 * HEADS + h];
        u1 = *(const uint4*)&h1b[(size_t)s1 * 32 + h * 4];
    }
    if (i + 16 < deg) s2 = csr_src[start + i + 16];

    for (; i < deg; i += 8) {
        int s3 = 0;
        if (i + 24 < deg) s3 = csr_src[start + i + 24];
        float e2 = 0.f;
        uint4 u2 = make_uint4(0u, 0u, 0u, 0u);
        if (i + 16 < deg) {
            e2 = als[s2 * HEADS + h];
            u2 = *(const uint4*)&h1b[(size_t)s2 * 32 + h * 4];
        }
        const float w = __expf(lrelu(e0 + aldn));
        const float2 p0 = unpack_bf16x2(u0.x);
        const float2 p1 = unpack_bf16x2(u0.y);
        const float2 p2 = unpack_bf16x2(u0.z);
        const float2 p3 = unpack_bf16x2(u0.w);
        a0 = fmaf(p0.x, w, a0); a1 = fmaf(p0.y, w, a1);
        a2 = fmaf(p1.x, w, a2); a3 = fmaf(p1.y, w, a3);
        a4 = fmaf(p2.x, w, a4); a5 = fmaf(p2.y, w, a5);
        a6 = fmaf(p3.x, w, a6); a7 = fmaf(p3.y, w, a7);
        wsum += w;
        e0 = e1; u0 = u1; e1 = e2; u1 = u2; s2 = s3;
    }

    // reduce across the 8 slots (8-lane groups)
    a0 += __shfl_down(a0, 32, 64); a1 += __shfl_down(a1, 32, 64);
    a2 += __shfl_down(a2, 32, 64); a3 += __shfl_down(a3, 32, 64);
    a4 += __shfl_down(a4, 32, 64); a5 += __shfl_down(a5, 32, 64);
    a6 += __shfl_down(a6, 32, 64); a7 += __shfl_down(a7, 32, 64);
    wsum += __shfl_down(wsum, 32, 64);
    a0 += __shfl_down(a0, 16, 64); a1 += __shfl_down(a1, 16, 64);
    a2 += __shfl_down(a2, 16, 64); a3 += __shfl_down(a3, 16, 64);
    a4 += __shfl_down(a4, 16, 64); a5 += __shfl_down(a5, 16, 64);
    a6 += __shfl_down(a6, 16, 64); a7 += __shfl_down(a7, 16, 64);
    wsum += __shfl_down(wsum, 16, 64);
    a0 += __shfl_down(a0, 8, 64); a1 += __shfl_down(a1, 8, 64);
    a2 += __shfl_down(a2, 8, 64); a3 += __shfl_down(a3, 8, 64);
    a4 += __shfl_down(a4, 8, 64); a5 += __shfl_down(a5, 8, 64);
    a6 += __shfl_down(a6, 8, 64); a7 += __shfl_down(a7, 8, 64);
    wsum += __shfl_down(wsum, 8, 64);

    // ---- fused layer2 (wave-local; fast_elu = single v_exp, r17 lesson) ----
    if (l < 8) {                                  // lane l holds channels 8l..8l+7
        const float inv = 1.f / (wsum + 1e-16f);
        const float4 b1a = *(const float4*)&b1[l * 8];
        const float4 b1b = *(const float4*)&b1[l * 8 + 4];
        const float z0 = fast_elu(a0 * inv + b1a.x);
        const float z1 = fast_elu(a1 * inv + b1a.y);
        const float z2 = fast_elu(a2 * inv + b1a.z);
        const float z3 = fast_elu(a3 * inv + b1a.w);
        const float z4 = fast_elu(a4 * inv + b1b.x);
        const float z5 = fast_elu(a5 * inv + b1b.y);
        const float z6 = fast_elu(a6 * inv + b1b.z);
        const float z7 = fast_elu(a7 * inv + b1b.w);
        *(float4*)&zbuf[wv][l * 8]     = make_float4(z0, z1, z2, z3);
        *(float4*)&zbuf[wv][l * 8 + 4] = make_float4(z4, z5, z6, z7);
    }
    __builtin_amdgcn_wave_barrier();             // pin DS write<->read program order
    asm volatile("" ::: "memory");               // forbid compiler value-forwarding

    // y[c] = sum_k z[k] * W2[k][c]; W2 direct from global (L1/L2-hot, r9-verified),
    // 4 partial accumulators to break the serial fmaf chain.
    const int c = l & 31;                         // output class
    const int kh = l >> 5;                        // k-half
    float y0 = 0.f, y1 = 0.f, y2 = 0.f, y3 = 0.f;
    const float* wbase = &W2[(kh * 32) * NCLASS + c];
#pragma unroll
    for (int j4 = 0; j4 < 2; j4++) {
        const int k0 = j4 * 16;
        const float4 za = *(const float4*)&zbuf[wv][kh * 32 + k0];
        const float4 zb = *(const float4*)&zbuf[wv][kh * 32 + k0 + 4];
        const float4 zc = *(const float4*)&zbuf[wv][kh * 32 + k0 + 8];
        const float4 zd = *(const float4*)&zbuf[wv][kh * 32 + k0 + 12];
        y0 = fmaf(za.x, wbase[(k0 + 0) * NCLASS], y0);
        y1 = fmaf(za.y, wbase[(k0 + 1) * NCLASS], y1);
        y2 = fmaf(za.z, wbase[(k0 + 2) * NCLASS], y2);
        y3 = fmaf(za.w, wbase[(k0 + 3) * NCLASS], y3);
        y0 = fmaf(zb.x, wbase[(k0 + 4) * NCLASS], y0);
        y1 = fmaf(zb.y, wbase[(k0 + 5) * NCLASS], y1);
        y2 = fmaf(zb.z, wbase[(k0 + 6) * NCLASS], y2);
        y3 = fmaf(zb.w, wbase[(k0 + 7) * NCLASS], y3);
        y0 = fmaf(zc.x, wbase[(k0 + 8) * NCLASS], y0);
        y1 = fmaf(zc.y, wbase[(k0 + 9) * NCLASS], y1);
        y2 = fmaf(zc.z, wbase[(k0 + 10) * NCLASS], y2);
        y3 = fmaf(zc.w, wbase[(k0 + 11) * NCLASS], y3);
        y0 = fmaf(zd.x, wbase[(k0 + 12) * NCLASS], y0);
        y1 = fmaf(zd.y, wbase[(k0 + 13) * NCLASS], y1);
        y2 = fmaf(zd.z, wbase[(k0 + 14) * NCLASS], y2);
        y3 = fmaf(zd.w, wbase[(k0 + 15) * NCLASS], y3);
    }
    float y = (y0 + y1) + (y2 + y3);
    y += __shfl_xor(y, 32, 64);                   // full y[c] on all lanes

    // layer-2 logit dots: lower half reduces y*a_src2, upper half y*a_dst2
    // (one 5-level tree within each 32-lane half; xor<32 stays in-half)
    float part = y * ((l < 32) ? a_src2[c] : a_dst2[c]);
    part += __shfl_xor(part, 1, 64);
    part += __shfl_xor(part, 2, 64);
    part += __shfl_xor(part, 4, 64);
    part += __shfl_xor(part, 8, 64);
    part += __shfl_xor(part, 16, 64);
    const float tdv = __shfl(part, 32, 64);       // td (upper-half sum)
    if (l == 0) { als2[n] = part; ald2[n] = tdv; }

    // pack h2 bf16: even lanes of lower half pack (y[c], y[c+1]) -> word c>>1
    const unsigned pw = pack_bf16x2(y, __shfl_down(y, 1, 64));
    if (l < 32 && (l & 1) == 0) h2b[(size_t)n * 16 + (l >> 1)] = pw;
}

// ---------------- K5: gather layer 2 + FUSED log_softmax ----------------
// Gather: wave/node, 4 lanes x uint4 (8ch), 16 edge slots, 2-deep pipeline.
// Epilogue: +b2, shfl-max, shfl-sum-exp over the 4-lane group, write final out.
__global__ __launch_bounds__(256) void gather2_kernel(const int* __restrict__ row_ptr,
                                                      const int* __restrict__ cnt,
                                                      const int* __restrict__ csr_src,
                                                      const unsigned* __restrict__ h2b,
                                                      const float* __restrict__ als2,
                                                      const float* __restrict__ ald2,
                                                      const float* __restrict__ b2,
                                                      float* __restrict__ out) {
    const int tid = threadIdx.x;
    const int n = blockIdx.x * 4 + (tid >> 6);   // grid == N_NODES/4 exactly
    const int l = tid & 63;
    const int q = l >> 2;                        // edge slot 0..15
    const int c = l & 3;                         // channel octet: ch 8c..8c+7
    const int start = row_ptr[n];
    const int deg = cnt[n];
    const float aldn = ald2[n];
    float a0 = 0.f, a1 = 0.f, a2 = 0.f, a3 = 0.f;
    float a4 = 0.f, a5 = 0.f, a6 = 0.f, a7 = 0.f, wsum = 0.f;

    int i = q;
    float e0 = 0.f, e1 = 0.f;
    uint4 u0 = make_uint4(0u, 0u, 0u, 0u);
    uint4 u1 = make_uint4(0u, 0u, 0u, 0u);
    int s2 = 0;
    if (i < deg) {
        const int s0 = csr_src[start + i];
        e0 = als2[s0];
        u0 = *(const uint4*)&h2b[(size_t)s0 * 16 + c * 4];
    }
    if (i + 16 < deg) {
        const int s1 = csr_src[start + i + 16];
        e1 = als2[s1];
        u1 = *(const uint4*)&h2b[(size_t)s1 * 16 + c * 4];
    }
    if (i + 32 < deg) s2 = csr_src[start + i + 32];

    for (; i < deg; i += 16) {
        int s3 = 0;
        if (i + 48 < deg) s3 = csr_src[start + i + 48];
        float e2 = 0.f;
        uint4 u2 = make_uint4(0u, 0u, 0u, 0u);
        if (i + 32 < deg) {
            e2 = als2[s2];
            u2 = *(const uint4*)&h2b[(size_t)s2 * 16 + c * 4];
        }
        const float w = __expf(lrelu(e0 + aldn));
        const float2 p0 = unpack_bf16x2(u0.x);
        const float2 p1 = unpack_bf16x2(u0.y);
        const float2 p2 = unpack_bf16x2(u0.z);
        const float2 p3 = unpack_bf16x2(u0.w);
        a0 = fmaf(p0.x, w, a0); a1 = fmaf(p0.y, w, a1);
        a2 = fmaf(p1.x, w, a2); a3 = fmaf(p1.y, w, a3);
        a4 = fmaf(p2.x, w, a4); a5 = fmaf(p2.y, w, a5);
        a6 = fmaf(p3.x, w, a6); a7 = fmaf(p3.y, w, a7);
        wsum += w;
        e0 = e1; u0 = u1; e1 = e2; u1 = u2; s2 = s3;
    }

    // reduce across the 16 slots (4-lane groups)
    a0 += __shfl_down(a0, 32, 64); a1 += __shfl_down(a1, 32, 64);
    a2 += __shfl_down(a2, 32, 64); a3 += __shfl_down(a3, 32, 64);
    a4 += __shfl_down(a4, 32, 64); a5 += __shfl_down(a5, 32, 64);
    a6 += __shfl_down(a6, 32, 64); a7 += __shfl_down(a7, 32, 64);
    wsum += __shfl_down(wsum, 32, 64);
    a0 += __shfl_down(a0, 16, 64); a1 += __shfl_down(a1, 16, 64);
    a2 += __shfl_down(a2, 16, 64); a3 += __shfl_down(a3, 16, 64);
    a4 += __shfl_down(a4, 16, 64); a5 += __shfl_down(a5, 16, 64);
    a6 += __shfl_down(a6, 16, 64); a7 += __shfl_down(a7, 16, 64);
    wsum += __shfl_down(wsum, 16, 64);
    a0 += __shfl_down(a0, 8, 64); a1 += __shfl_down(a1, 8, 64);
    a2 += __shfl_down(a2, 8, 64); a3 += __shfl_down(a3, 8, 64);
    a4 += __shfl_down(a4, 8, 64); a5 += __shfl_down(a5, 8, 64);
    a6 += __shfl_down(a6, 8, 64); a7 += __shfl_down(a7, 8, 64);
    wsum += __shfl_down(wsum, 8, 64);
    a0 += __shfl_down(a0, 4, 64); a1 += __shfl_down(a1, 4, 64);
    a2 += __shfl_down(a2, 4, 64); a3 += __shfl_down(a3, 4, 64);
    a4 += __shfl_down(a4, 4, 64); a5 += __shfl_down(a5, 4, 64);
    a6 += __shfl_down(a6, 4, 64); a7 += __shfl_down(a7, 4, 64);
    wsum += __shfl_down(wsum, 4, 64);

    // ---- fused +b2 and log_softmax over the 4-lane group ----
    const float inv = 1.f / (wsum + 1e-16f);
    const float4 b2a = *(const float4*)&b2[c * 8];
    const float4 b2b = *(const float4*)&b2[c * 8 + 4];
    const float v0 = a0 * inv + b2a.x, v1 = a1 * inv + b2a.y;
    const float v2 = a2 * inv + b2a.z, v3 = a3 * inv + b2a.w;
    const float v4 = a4 * inv + b2b.x, v5 = a5 * inv + b2b.y;
    const float v6 = a6 * inv + b2b.z, v7 = a7 * inv + b2b.w;
    float mx = fmaxf(fmaxf(fmaxf(v0, v1), fmaxf(v2, v3)),
                     fmaxf(fmaxf(v4, v5), fmaxf(v6, v7)));
    mx = fmaxf(mx, __shfl_xor(mx, 1, 64));
    mx = fmaxf(mx, __shfl_xor(mx, 2, 64));
    float s = __expf(v0 - mx) + __expf(v1 - mx) + __expf(v2 - mx) + __expf(v3 - mx)
            + __expf(v4 - mx) + __expf(v5 - mx) + __expf(v6 - mx) + __expf(v7 - mx);
    s += __shfl_xor(s, 1, 64);
    s += __shfl_xor(s, 2, 64);
    const float lse = mx + logf(s);
    if (l < 4) {
        float* op = &out[(size_t)n * NCLASS + c * 8];
        *(float4*)&op[0] = make_float4(v0 - lse, v1 - lse, v2 - lse, v3 - lse);
        *(float4*)&op[4] = make_float4(v4 - lse, v5 - lse, v6 - lse, v7 - lse);
    }
}

extern "C" void kernel_launch(void* const* d_in, const int* in_sizes, int n_in,
                              void* d_out, int out_size, void* d_ws, size_t ws_size,
                              hipStream_t stream) {
    const float* x      = (const float*)d_in[0];
    const int*   ei     = (const int*)d_in[1];
    const float* W1     = (const float*)d_in[2];
    const float* a_src1 = (const float*)d_in[3];
    const float* a_dst1 = (const float*)d_in[4];
    const float* b1     = (const float*)d_in[5];
    const float* W2     = (const float*)d_in[6];
    const float* a_src2 = (const float*)d_in[7];
    const float* a_dst2 = (const float*)d_in[8];
    const float* b2     = (const float*)d_in[9];
    float* out = (float*)d_out;
    float* ws  = (float*)d_ws;

    ushort* h1u     = (ushort*)(ws + OFF_H1);
    unsigned* h1b   = (unsigned*)(ws + OFF_H1);
    unsigned* h2b   = (unsigned*)(ws + OFF_H2);          // distinct region: h1b still live in gather1
    float* als1     = ws + OFF_ALS1;
    float* ald1     = ws + OFF_ALD1;
    float* als2     = ws + OFF_ALS2;
    float* ald2     = ws + OFF_ALD2;
    int*   bcur     = (int*)(ws + OFF_BCUR);
    int*   row_ptr  = (int*)(ws + OFF_ROWP);
    int*   cnt      = (int*)(ws + OFF_CNT);
    int*   bin      = (int*)(ws + OFF_BIN);
    int*   csr      = (int*)(ws + OFF_CSR);

    hipMemsetAsync(bcur, 0, NBUCK * sizeof(int), stream);

    gemm1_kernel<<<(N_NODES + 63) / 64, 256, 0, stream>>>(x, W1, a_src1, a_dst1, h1u, als1, ald1);
    bin_kernel<<<(E_TOT + BIN_EPB - 1) / BIN_EPB, 256, 0, stream>>>(ei, bcur, bin);
    bsort_kernel<<<NBUCK, 256, 0, stream>>>(bcur, bin, csr, row_ptr, cnt);
    gather1_kernel<<<N_NODES / 4, 256, 0, stream>>>(row_ptr, cnt, csr, h1b, als1, ald1,
                                                    b1, W2, a_src2, a_dst2, h2b, als2, ald2);
    gather2_kernel<<<N_NODES / 4, 256, 0, stream>>>(row_ptr, cnt, csr, h2b, als2, ald2, b2, out);
}

// Round 12
// 329.361 us; speedup vs baseline: 1.0733x; 1.0232x over previous
//
#include <hip/hip_runtime.h>
#include <math.h>

#define N_NODES 100000
#define NFEAT 256
#define D1 64          // HEADS*NHID
#define HEADS 8
#define NHID 8
#define NCLASS 32
#define NUM_EDGES 1600000
#define E_TOT 1700000  // + self loops
#define NEG_SLOPE 0.2f

// dst-bucketing: 256 nodes per bucket; CSR stored bucket-strided (no compaction)
#define BSHIFT 8
#define NBUCK 391            // ceil(100000/256)
#define BCAP 5120            // mean edges/bucket 4352, std ~66; +11.6 sigma headroom
#define BIN_EPB 4096
#define BIN_EPT 16
#define GEMM1_NB 1563        // ceil(100000/64)

// LESSON (r4): wave-per-node x 25k waves >> block-per-bucket (TLP hides gather latency).
// LESSON (r9): gather MLP fix (edge slots + vector loads + pipeline) 76->63us.
// LESSON (r10-r13): gemm1 — source-level pipelining only sticks when __syncthreads()
// sits between load-issue and use; LDS double-buffer + one barrier/chunk WORKED.
// LESSON (r14/r16): 8-slot uint4 gathers + 2-deep pipeline: gather1 out of top-5 (<60us).
// LESSON (r16): fused layer2 into gather1 / logsoftmax into gather2 (7->5 dispatches).
// LESSON (r17): expm1f = ~30-instr libm expansion; fast_elu recovered 96->87us.
// LESSON (r19/r20): epilogue cost is NOT dot throughput (LDS-W2 + partials = null).
// LESSON (r21): __syncthreads in the fused epilogue convoyed waves device-wide (HBM
// 2.9->1.8 TB/s, same bytes). Barrier-free wave-local epilogue (zbuf per-wave +
// wave_barrier fence): 90->74us, total 337. gather1 now VALU-bound (VALU 82%, HBM 27%).
// LESSON (r22): remaining lever = pipeline concurrency. Dependency graph: bsort needs
// only bin; gemm1 independent. Multi-stream/events forbidden (graph capture), so use
// role-split block fusion: bin first, then ONE kernel = {blocks 0..390: bsort,
// 391..1953: gemm1}. Stream order keeps bin->bsort; bsort hides under gemm1.

// ---- workspace layout (float offsets); h1/h2 are PACKED BF16 (uint = 2 ch) ----
#define OFF_H1    0            // h1b: 3.2M uints
#define OFF_H2    6400000      // h2b: 1.6M uints (old out1 region; h1b still live in gather1)
#define OFF_ALS1  12800000
#define OFF_ALD1  13600000
#define OFF_ALS2  14400000
#define OFF_ALD2  14500000
#define OFF_BCUR  14600000     // 391 ints (pad to 1024)
#define OFF_ROWP  14601024
#define OFF_CNT   14701024
#define OFF_BIN   14801024     // 391*5120 ints (packed dl<<20|src)
#define OFF_CSR   16802944     // 391*5120 ints (dst-sorted src)

typedef __attribute__((ext_vector_type(8))) short bf16x8;
typedef __attribute__((ext_vector_type(4))) float f32x4;

__device__ __forceinline__ float lrelu(float x) { return x >= 0.f ? x : NEG_SLOPE * x; }
__device__ __forceinline__ float fast_elu(float x) { return x > 0.f ? x : __expf(x) - 1.f; }

__device__ __forceinline__ unsigned f32_to_bf16_rne(float f) {
    unsigned u = __float_as_uint(f);
    return (u + 0x7fffu + ((u >> 16) & 1u)) >> 16;
}
__device__ __forceinline__ unsigned pack_bf16x2(float lo, float hi) {
    return f32_to_bf16_rne(lo) | (f32_to_bf16_rne(hi) << 16);
}
__device__ __forceinline__ float2 unpack_bf16x2(unsigned v) {
    return make_float2(__uint_as_float(v << 16), __uint_as_float(v & 0xffff0000u));
}

__device__ __forceinline__ void edge_src_dst(const int* __restrict__ ei, int e, int& src, int& dst) {
    if (e < NUM_EDGES) { src = ei[e]; dst = ei[NUM_EDGES + e]; }
    else { src = e - NUM_EDGES; dst = e - NUM_EDGES; }
}

// ---------------- K2: bin edges by dst bucket (LDS hist + chunk reservation) ----------------
// packed entry: (dst&255)<<20 | src   (src < 2^17)
__global__ __launch_bounds__(256) void bin_kernel(const int* __restrict__ ei,
                                                  int* __restrict__ bcur,
                                                  int* __restrict__ bin) {
    __shared__ int lcnt[NBUCK];
    __shared__ int lbase[NBUCK];
    const int tid = threadIdx.x;
    for (int b = tid; b < NBUCK; b += 256) lcnt[b] = 0;
    __syncthreads();
    const int e0 = blockIdx.x * BIN_EPB;
    int pk[BIN_EPT], bk[BIN_EPT], loff[BIN_EPT];
#pragma unroll
    for (int i = 0; i < BIN_EPT; i++) {
        const int e = e0 + i * 256 + tid;
        if (e < E_TOT) {
            int src, dst; edge_src_dst(ei, e, src, dst);
            bk[i] = dst >> BSHIFT;
            pk[i] = ((dst & 255) << 20) | src;
            loff[i] = atomicAdd(&lcnt[bk[i]], 1);
        } else bk[i] = -1;
    }
    __syncthreads();
    for (int b = tid; b < NBUCK; b += 256) {
        const int c = lcnt[b];
        lbase[b] = c ? atomicAdd(&bcur[b], c) : 0;
    }
    __syncthreads();
#pragma unroll
    for (int i = 0; i < BIN_EPT; i++) {
        if (bk[i] >= 0)
            bin[(size_t)bk[i] * BCAP + lbase[bk[i]] + loff[i]] = pk[i];
    }
}

// ---------------- K1+K3 merged: role-split blocks -------------------------------------
// blocks [0, NBUCK)           : per-bucket LDS counting sort (depends on bin_kernel,
//                               satisfied by stream order)
// blocks [NBUCK, NBUCK+1563)  : gemm1 h1 = x @ W1 MFMA + fused logit dots (independent)
// LDS: 23552-byte union (bsort footprint; gemm1 uses 10240 of it).
// No inter-role sync; disjoint outputs; __syncthreads only within uniform role branches.
__global__ __launch_bounds__(256) void gemm1_bsort_kernel(const float* __restrict__ x,
                                                          const float* __restrict__ W1,
                                                          const float* __restrict__ a_src,
                                                          const float* __restrict__ a_dst,
                                                          ushort* __restrict__ h1u,
                                                          float* __restrict__ als,
                                                          float* __restrict__ ald,
                                                          const int* __restrict__ bcur,
                                                          const int* __restrict__ bin,
                                                          int* __restrict__ csr,
                                                          int* __restrict__ row_ptr,
                                                          int* __restrict__ cnt) {
    __shared__ __align__(16) unsigned char smem[23552];
    const int tid = threadIdx.x;

    if (blockIdx.x < NBUCK) {
        // ---- bsort role ----
        int* hcnt = (int*)smem;          // 256
        int* hpre = hcnt + 256;          // 256
        int* curp = hpre + 256;          // 256
        int* ssrc = curp + 256;          // BCAP (20 KB)
        const int bkt = blockIdx.x;
        const int cntb = bcur[bkt];
        const int base = bkt * BCAP;
        hcnt[tid] = 0;
        __syncthreads();
        for (int i = tid; i < cntb; i += 256)
            atomicAdd(&hcnt[bin[base + i] >> 20], 1);
        __syncthreads();
        const int myc = hcnt[tid];
        hpre[tid] = myc;
        __syncthreads();
        for (int off = 1; off < 256; off <<= 1) {
            const int t = (tid >= off) ? hpre[tid - off] : 0;
            __syncthreads();
            hpre[tid] += t;
            __syncthreads();
        }
        const int exc = hpre[tid] - myc;
        curp[tid] = exc;
        __syncthreads();
        for (int i = tid; i < cntb; i += 256) {
            const int v = bin[base + i];
            const int pos = atomicAdd(&curp[v >> 20], 1);
            ssrc[pos] = v & 0xFFFFF;
        }
        __syncthreads();
        for (int i = tid; i < cntb; i += 256) csr[base + i] = ssrc[i];
        const int n = (bkt << BSHIFT) + tid;
        if (n < N_NODES) { row_ptr[n] = base + exc; cnt[n] = myc; }
        return;
    }

    // ---- gemm1 role ----
    unsigned* xbf = (unsigned*)smem;     // [2][64*20] uints (10240 B)
    const int wv = tid >> 6;             // wave = col-tile
    const int l = tid & 63;
    const int lm = l & 15;
    const int quad = l >> 4;
    const int r0 = (blockIdx.x - NBUCK) * 64;

    // B-fragments: this wave's 16-col slice of W1, all 8 K-chunks, in registers (32 VGPRs)
    bf16x8 bfrag[8];
#pragma unroll
    for (int kb = 0; kb < 8; kb++)
#pragma unroll
        for (int j = 0; j < 8; j++) {
            const int k = kb * 32 + quad * 8 + j;
            bfrag[kb][j] = (short)f32_to_bf16_rne(W1[k * D1 + wv * 16 + lm]);
        }

    f32x4 acc[4];
#pragma unroll
    for (int s = 0; s < 4; s++) acc[s] = (f32x4)(0.f);

    const int sr = tid >> 2;            // staging: row 0..63
    const int sk = (tid & 3) * 8;       // k-offset within 32-chunk
    const bool rok = (r0 + sr) < N_NODES;
    const float* xrow = &x[(size_t)(r0 + sr) * NFEAT];
    const int swrd = sr * 20 + (tid & 3) * 4;   // LDS write word offset

    // prologue: load + pack + write chunk 0 into buf 0
    {
        uint4 pv = make_uint4(0, 0, 0, 0);
        if (rok) {
            const float4 va = *(const float4*)&xrow[sk];
            const float4 vb = *(const float4*)&xrow[sk + 4];
            pv.x = pack_bf16x2(va.x, va.y);
            pv.y = pack_bf16x2(va.z, va.w);
            pv.z = pack_bf16x2(vb.x, vb.y);
            pv.w = pack_bf16x2(vb.z, vb.w);
        }
        *(uint4*)&xbf[swrd] = pv;
    }
    __syncthreads();

#pragma unroll
    for (int kb = 0; kb < 8; kb++) {
        const int cur = kb & 1;
        const int nxt = cur ^ 1;
        // issue next chunk's global loads (in flight during the MFMA phase below;
        // the barrier between issue and use pins this order against the scheduler)
        float4 na = make_float4(0.f, 0.f, 0.f, 0.f);
        float4 nb = make_float4(0.f, 0.f, 0.f, 0.f);
        if (kb < 7 && rok) {
            na = *(const float4*)&xrow[(kb + 1) * 32 + sk];
            nb = *(const float4*)&xrow[(kb + 1) * 32 + sk + 4];
        }
        // MFMA phase: consume buf[cur]
#pragma unroll
        for (int s = 0; s < 4; s++) {
            const uint4 u = *(const uint4*)&xbf[cur * 1280 + (s * 16 + lm) * 20 + quad * 4];
            const bf16x8 af = *(const bf16x8*)&u;
            acc[s] = __builtin_amdgcn_mfma_f32_16x16x32_bf16(af, bfrag[kb], acc[s], 0, 0, 0);
        }
        // pack + write next chunk into the other buffer (no reader conflict), one barrier
        if (kb < 7) {
            uint4 pv;
            pv.x = pack_bf16x2(na.x, na.y);
            pv.y = pack_bf16x2(na.z, na.w);
            pv.z = pack_bf16x2(nb.x, nb.y);
            pv.w = pack_bf16x2(nb.z, nb.w);
            *(uint4*)&xbf[nxt * 1280 + swrd] = pv;
            __syncthreads();
        }
    }

    // epilogue: bf16 h1 stores + f32 logit dots (shfl over 8-lane head groups)
    const int head = wv * 2 + (lm >> 3);
    const int jc = l & 7;
    const float asl = a_src[head * NHID + jc];
    const float adl = a_dst[head * NHID + jc];
    const int col = wv * 16 + lm;
#pragma unroll
    for (int s = 0; s < 4; s++) {
#pragma unroll
        for (int r = 0; r < 4; r++) {
            const int row = r0 + s * 16 + quad * 4 + r;
            const float v = acc[s][r];
            float ps = v * asl, pd = v * adl;
            ps += __shfl_xor(ps, 1, 64); pd += __shfl_xor(pd, 1, 64);
            ps += __shfl_xor(ps, 2, 64); pd += __shfl_xor(pd, 2, 64);
            ps += __shfl_xor(ps, 4, 64); pd += __shfl_xor(pd, 4, 64);
            if (row < N_NODES) {
                h1u[(size_t)row * D1 + col] = (ushort)f32_to_bf16_rne(v);
                if (jc == 0) { als[row * HEADS + head] = ps; ald[row * HEADS + head] = pd; }
            }
        }
    }
}

// ---------------- K4: gather layer 1 + FUSED layer2 (barrier-free epilogue) ----------------
// Gather: wave/node, 8 lanes x uint4 (head octet), 8 edge slots, 2-deep value pipeline,
// unroll-2 so regalloc ping-pongs pipeline registers instead of emitting moves.
// Epilogue is WAVE-LOCAL (r21): zbuf[wv] + wave_barrier fence, NO __syncthreads.
__global__ __launch_bounds__(256) void gather1_kernel(const int* __restrict__ row_ptr,
                                                      const int* __restrict__ cnt,
                                                      const int* __restrict__ csr_src,
                                                      const unsigned* __restrict__ h1b,
                                                      const float* __restrict__ als,
                                                      const float* __restrict__ ald,
                                                      const float* __restrict__ b1,
                                                      const float* __restrict__ W2,
                                                      const float* __restrict__ a_src2,
                                                      const float* __restrict__ a_dst2,
                                                      unsigned* __restrict__ h2b,
                                                      float* __restrict__ als2,
                                                      float* __restrict__ ald2) {
    __shared__ float zbuf[4][64];                // per-wave z row (1 KB)
    const int tid = threadIdx.x;
    const int wv = tid >> 6;
    const int n = blockIdx.x * 4 + wv;           // grid == N_NODES/4 exactly
    const int l = tid & 63;
    const int q = l >> 3;                        // edge slot 0..7
    const int h = l & 7;                         // head = channel octet 8h..8h+7
    const int start = row_ptr[n];
    const int deg = cnt[n];
    const float aldn = ald[n * HEADS + h];
    float a0 = 0.f, a1 = 0.f, a2 = 0.f, a3 = 0.f;
    float a4 = 0.f, a5 = 0.f, a6 = 0.f, a7 = 0.f, wsum = 0.f;

    int i = q;
    float e0 = 0.f, e1 = 0.f;
    uint4 u0 = make_uint4(0u, 0u, 0u, 0u);
    uint4 u1 = make_uint4(0u, 0u, 0u, 0u);
    int s2 = 0;
    if (i < deg) {
        const int s0 = csr_src[start + i];
        e0 = als[s0 * HEADS + h];
        u0 = *(const uint4*)&h1b[(size_t)s0 * 32 + h * 4];
    }
    if (i + 8 < deg) {
        const int s1 = csr_src[start + i + 8];
        e1 = als[s1 * HEADS + h];
        u1 = *(const uint4*)&h1b[(size_t)s1 * 32 + h * 4];
    }
    if (i + 16 < deg) s2 = csr_src[start + i + 16];

#pragma unroll 2
    for (; i < deg; i += 8) {
        int s3 = 0;
        if (i + 24 < deg) s3 = csr_src[start + i + 24];
        float e2 = 0.f;
        uint4 u2 = make_uint4(0u, 0u, 0u, 0u);
        if (i + 16 < deg) {
            e2 = als[s2 * HEADS + h];
            u2 = *(const uint4*)&h1b[(size_t)s2 * 32 + h * 4];
        }
        const float w = __expf(lrelu(e0 + aldn));
        const float2 p0 = unpack_bf16x2(u0.x);
        const float2 p1 = unpack_bf16x2(u0.y);
        const float2 p2 = unpack_bf16x2(u0.z);
        const float2 p3 = unpack_bf16x2(u0.w);
        a0 = fmaf(p0.x, w, a0); a1 = fmaf(p0.y, w, a1);
        a2 = fmaf(p1.x, w, a2); a3 = fmaf(p1.y, w, a3);
        a4 = fmaf(p2.x, w, a4); a5 = fmaf(p2.y, w, a5);
        a6 = fmaf(p3.x, w, a6); a7 = fmaf(p3.y, w, a7);
        wsum += w;
        e0 = e1; u0 = u1; e1 = e2; u1 = u2; s2 = s3;
    }

    // reduce across the 8 slots (8-lane groups)
    a0 += __shfl_down(a0, 32, 64); a1 += __shfl_down(a1, 32, 64);
    a2 += __shfl_down(a2, 32, 64); a3 += __shfl_down(a3, 32, 64);
    a4 += __shfl_down(a4, 32, 64); a5 += __shfl_down(a5, 32, 64);
    a6 += __shfl_down(a6, 32, 64); a7 += __shfl_down(a7, 32, 64);
    wsum += __shfl_down(wsum, 32, 64);
    a0 += __shfl_down(a0, 16, 64); a1 += __shfl_down(a1, 16, 64);
    a2 += __shfl_down(a2, 16, 64); a3 += __shfl_down(a3, 16, 64);
    a4 += __shfl_down(a4, 16, 64); a5 += __shfl_down(a5, 16, 64);
    a6 += __shfl_down(a6, 16, 64); a7 += __shfl_down(a7, 16, 64);
    wsum += __shfl_down(wsum, 16, 64);
    a0 += __shfl_down(a0, 8, 64); a1 += __shfl_down(a1, 8, 64);
    a2 += __shfl_down(a2, 8, 64); a3 += __shfl_down(a3, 8, 64);
    a4 += __shfl_down(a4, 8, 64); a5 += __shfl_down(a5, 8, 64);
    a6 += __shfl_down(a6, 8, 64); a7 += __shfl_down(a7, 8, 64);
    wsum += __shfl_down(wsum, 8, 64);

    // ---- fused layer2 (wave-local; fast_elu = single v_exp, r17 lesson) ----
    if (l < 8) {                                  // lane l holds channels 8l..8l+7
        const float inv = 1.f / (wsum + 1e-16f);
        const float4 b1a = *(const float4*)&b1[l * 8];
        const float4 b1b = *(const float4*)&b1[l * 8 + 4];
        const float z0 = fast_elu(a0 * inv + b1a.x);
        const float z1 = fast_elu(a1 * inv + b1a.y);
        const float z2 = fast_elu(a2 * inv + b1a.z);
        const float z3 = fast_elu(a3 * inv + b1a.w);
        const float z4 = fast_elu(a4 * inv + b1b.x);
        const float z5 = fast_elu(a5 * inv + b1b.y);
        const float z6 = fast_elu(a6 * inv + b1b.z);
        const float z7 = fast_elu(a7 * inv + b1b.w);
        *(float4*)&zbuf[wv][l * 8]     = make_float4(z0, z1, z2, z3);
        *(float4*)&zbuf[wv][l * 8 + 4] = make_float4(z4, z5, z6, z7);
    }
    __builtin_amdgcn_wave_barrier();             // pin DS write<->read program order
    asm volatile("" ::: "memory");               // forbid compiler value-forwarding

    // y[c] = sum_k z[k] * W2[k][c]; W2 direct from global (L1/L2-hot, r9-verified),
    // 4 partial accumulators to break the serial fmaf chain.
    const int c = l & 31;                         // output class
    const int kh = l >> 5;                        // k-half
    float y0 = 0.f, y1 = 0.f, y2 = 0.f, y3 = 0.f;
    const float* wbase = &W2[(kh * 32) * NCLASS + c];
#pragma unroll
    for (int j4 = 0; j4 < 2; j4++) {
        const int k0 = j4 * 16;
        const float4 za = *(const float4*)&zbuf[wv][kh * 32 + k0];
        const float4 zb = *(const float4*)&zbuf[wv][kh * 32 + k0 + 4];
        const float4 zc = *(const float4*)&zbuf[wv][kh * 32 + k0 + 8];
        const float4 zd = *(const float4*)&zbuf[wv][kh * 32 + k0 + 12];
        y0 = fmaf(za.x, wbase[(k0 + 0) * NCLASS], y0);
        y1 = fmaf(za.y, wbase[(k0 + 1) * NCLASS], y1);
        y2 = fmaf(za.z, wbase[(k0 + 2) * NCLASS], y2);
        y3 = fmaf(za.w, wbase[(k0 + 3) * NCLASS], y3);
        y0 = fmaf(zb.x, wbase[(k0 + 4) * NCLASS], y0);
        y1 = fmaf(zb.y, wbase[(k0 + 5) * NCLASS], y1);
        y2 = fmaf(zb.z, wbase[(k0 + 6) * NCLASS], y2);
        y3 = fmaf(zb.w, wbase[(k0 + 7) * NCLASS], y3);
        y0 = fmaf(zc.x, wbase[(k0 + 8) * NCLASS], y0);
        y1 = fmaf(zc.y, wbase[(k0 + 9) * NCLASS], y1);
        y2 = fmaf(zc.z, wbase[(k0 + 10) * NCLASS], y2);
        y3 = fmaf(zc.w, wbase[(k0 + 11) * NCLASS], y3);
        y0 = fmaf(zd.x, wbase[(k0 + 12) * NCLASS], y0);
        y1 = fmaf(zd.y, wbase[(k0 + 13) * NCLASS], y1);
        y2 = fmaf(zd.z, wbase[(k0 + 14) * NCLASS], y2);
        y3 = fmaf(zd.w, wbase[(k0 + 15) * NCLASS], y3);
    }
    float y = (y0 + y1) + (y2 + y3);
    y += __shfl_xor(y, 32, 64);                   // full y[c] on all lanes

    // layer-2 logit dots: lower half reduces y*a_src2, upper half y*a_dst2
    // (one 5-level tree within each 32-lane half; xor<32 stays in-half)
    float part = y * ((l < 32) ? a_src2[c] : a_dst2[c]);
    part += __shfl_xor(part, 1, 64);
    part += __shfl_xor(part, 2, 64);
    part += __shfl_xor(part, 4, 64);
    part += __shfl_xor(part, 8, 64);
    part += __shfl_xor(part, 16, 64);
    const float tdv = __shfl(part, 32, 64);       // td (upper-half sum)
    if (l == 0) { als2[n] = part; ald2[n] = tdv; }

    // pack h2 bf16: even lanes of lower half pack (y[c], y[c+1]) -> word c>>1
    const unsigned pw = pack_bf16x2(y, __shfl_down(y, 1, 64));
    if (l < 32 && (l & 1) == 0) h2b[(size_t)n * 16 + (l >> 1)] = pw;
}

// ---------------- K5: gather layer 2 + FUSED log_softmax ----------------
// Gather: wave/node, 4 lanes x uint4 (8ch), 16 edge slots, 2-deep pipeline.
// Epilogue: +b2, shfl-max, shfl-sum-exp over the 4-lane group, write final out.
__global__ __launch_bounds__(256) void gather2_kernel(const int* __restrict__ row_ptr,
                                                      const int* __restrict__ cnt,
                                                      const int* __restrict__ csr_src,
                                                      const unsigned* __restrict__ h2b,
                                                      const float* __restrict__ als2,
                                                      const float* __restrict__ ald2,
                                                      const float* __restrict__ b2,
                                                      float* __restrict__ out) {
    const int tid = threadIdx.x;
    const int n = blockIdx.x * 4 + (tid >> 6);   // grid == N_NODES/4 exactly
    const int l = tid & 63;
    const int q = l >> 2;                        // edge slot 0..15
    const int c = l & 3;                         // channel octet: ch 8c..8c+7
    const int start = row_ptr[n];
    const int deg = cnt[n];
    const float aldn = ald2[n];
    float a0 = 0.f, a1 = 0.f, a2 = 0.f, a3 = 0.f;
    float a4 = 0.f, a5 = 0.f, a6 = 0.f, a7 = 0.f, wsum = 0.f;

    int i = q;
    float e0 = 0.f, e1 = 0.f;
    uint4 u0 = make_uint4(0u, 0u, 0u, 0u);
    uint4 u1 = make_uint4(0u, 0u, 0u, 0u);
    int s2 = 0;
    if (i < deg) {
        const int s0 = csr_src[start + i];
        e0 = als2[s0];
        u0 = *(const uint4*)&h2b[(size_t)s0 * 16 + c * 4];
    }
    if (i + 16 < deg) {
        const int s1 = csr_src[start + i + 16];
        e1 = als2[s1];
        u1 = *(const uint4*)&h2b[(size_t)s1 * 16 + c * 4];
    }
    if (i + 32 < deg) s2 = csr_src[start + i + 32];

#pragma unroll 2
    for (; i < deg; i += 16) {
        int s3 = 0;
        if (i + 48 < deg) s3 = csr_src[start + i + 48];
        float e2 = 0.f;
        uint4 u2 = make_uint4(0u, 0u, 0u, 0u);
        if (i + 32 < deg) {
            e2 = als2[s2];
            u2 = *(const uint4*)&h2b[(size_t)s2 * 16 + c * 4];
        }
        const float w = __expf(lrelu(e0 + aldn));
        const float2 p0 = unpack_bf16x2(u0.x);
        const float2 p1 = unpack_bf16x2(u0.y);
        const float2 p2 = unpack_bf16x2(u0.z);
        const float2 p3 = unpack_bf16x2(u0.w);
        a0 = fmaf(p0.x, w, a0); a1 = fmaf(p0.y, w, a1);
        a2 = fmaf(p1.x, w, a2); a3 = fmaf(p1.y, w, a3);
        a4 = fmaf(p2.x, w, a4); a5 = fmaf(p2.y, w, a5);
        a6 = fmaf(p3.x, w, a6); a7 = fmaf(p3.y, w, a7);
        wsum += w;
        e0 = e1; u0 = u1; e1 = e2; u1 = u2; s2 = s3;
    }

    // reduce across the 16 slots (4-lane groups)
    a0 += __shfl_down(a0, 32, 64); a1 += __shfl_down(a1, 32, 64);
    a2 += __shfl_down(a2, 32, 64); a3 += __shfl_down(a3, 32, 64);
    a4 += __shfl_down(a4, 32, 64); a5 += __shfl_down(a5, 32, 64);
    a6 += __shfl_down(a6, 32, 64); a7 += __shfl_down(a7, 32, 64);
    wsum += __shfl_down(wsum, 32, 64);
    a0 += __shfl_down(a0, 16, 64); a1 += __shfl_down(a1, 16, 64);
    a2 += __shfl_down(a2, 16, 64); a3 += __shfl_down(a3, 16, 64);
    a4 += __shfl_down(a4, 16, 64); a5 += __shfl_down(a5, 16, 64);
    a6 += __shfl_down(a6, 16, 64); a7 += __shfl_down(a7, 16, 64);
    wsum += __shfl_down(wsum, 16, 64);
    a0 += __shfl_down(a0, 8, 64); a1 += __shfl_down(a1, 8, 64);
    a2 += __shfl_down(a2, 8, 64); a3 += __shfl_down(a3, 8, 64);
    a4 += __shfl_down(a4, 8, 64); a5 += __shfl_down(a5, 8, 64);
    a6 += __shfl_down(a6, 8, 64); a7 += __shfl_down(a7, 8, 64);
    wsum += __shfl_down(wsum, 8, 64);
    a0 += __shfl_down(a0, 4, 64); a1 += __shfl_down(a1, 4, 64);
    a2 += __shfl_down(a2, 4, 64); a3 += __shfl_down(a3, 4, 64);
    a4 += __shfl_down(a4, 4, 64); a5 += __shfl_down(a5, 4, 64);
    a6 += __shfl_down(a6, 4, 64); a7 += __shfl_down(a7, 4, 64);
    wsum += __shfl_down(wsum, 4, 64);

    // ---- fused +b2 and log_softmax over the 4-lane group ----
    const float inv = 1.f / (wsum + 1e-16f);
    const float4 b2a = *(const float4*)&b2[c * 8];
    const float4 b2b = *(const float4*)&b2[c * 8 + 4];
    const float v0 = a0 * inv + b2a.x, v1 = a1 * inv + b2a.y;
    const float v2 = a2 * inv + b2a.z, v3 = a3 * inv + b2a.w;
    const float v4 = a4 * inv + b2b.x, v5 = a5 * inv + b2b.y;
    const float v6 = a6 * inv + b2b.z, v7 = a7 * inv + b2b.w;
    float mx = fmaxf(fmaxf(fmaxf(v0, v1), fmaxf(v2, v3)),
                     fmaxf(fmaxf(v4, v5), fmaxf(v6, v7)));
    mx = fmaxf(mx, __shfl_xor(mx, 1, 64));
    mx = fmaxf(mx, __shfl_xor(mx, 2, 64));
    float s = __expf(v0 - mx) + __expf(v1 - mx) + __expf(v2 - mx) + __expf(v3 - mx)
            + __expf(v4 - mx) + __expf(v5 - mx) + __expf(v6 - mx) + __expf(v7 - mx);
    s += __shfl_xor(s, 1, 64);
    s += __shfl_xor(s, 2, 64);
    const float lse = mx + logf(s);
    if (l < 4) {
        float* op = &out[(size_t)n * NCLASS + c * 8];
        *(float4*)&op[0] = make_float4(v0 - lse, v1 - lse, v2 - lse, v3 - lse);
        *(float4*)&op[4] = make_float4(v4 - lse, v5 - lse, v6 - lse, v7 - lse);
    }
}

extern "C" void kernel_launch(void* const* d_in, const int* in_sizes, int n_in,
                              void* d_out, int out_size, void* d_ws, size_t ws_size,
                              hipStream_t stream) {
    const float* x      = (const float*)d_in[0];
    const int*   ei     = (const int*)d_in[1];
    const float* W1     = (const float*)d_in[2];
    const float* a_src1 = (const float*)d_in[3];
    const float* a_dst1 = (const float*)d_in[4];
    const float* b1     = (const float*)d_in[5];
    const float* W2     = (const float*)d_in[6];
    const float* a_src2 = (const float*)d_in[7];
    const float* a_dst2 = (const float*)d_in[8];
    const float* b2     = (const float*)d_in[9];
    float* out = (float*)d_out;
    float* ws  = (float*)d_ws;

    ushort* h1u     = (ushort*)(ws + OFF_H1);
    unsigned* h1b   = (unsigned*)(ws + OFF_H1);
    unsigned* h2b   = (unsigned*)(ws + OFF_H2);          // distinct region: h1b still live in gather1
    float* als1     = ws + OFF_ALS1;
    float* ald1     = ws + OFF_ALD1;
    float* als2     = ws + OFF_ALS2;
    float* ald2     = ws + OFF_ALD2;
    int*   bcur     = (int*)(ws + OFF_BCUR);
    int*   row_ptr  = (int*)(ws + OFF_ROWP);
    int*   cnt      = (int*)(ws + OFF_CNT);
    int*   bin      = (int*)(ws + OFF_BIN);
    int*   csr      = (int*)(ws + OFF_CSR);

    hipMemsetAsync(bcur, 0, NBUCK * sizeof(int), stream);

    bin_kernel<<<(E_TOT + BIN_EPB - 1) / BIN_EPB, 256, 0, stream>>>(ei, bcur, bin);
    gemm1_bsort_kernel<<<NBUCK + GEMM1_NB, 256, 0, stream>>>(x, W1, a_src1, a_dst1,
                                                             h1u, als1, ald1,
                                                             bcur, bin, csr, row_ptr, cnt);
    gather1_kernel<<<N_NODES / 4, 256, 0, stream>>>(row_ptr, cnt, csr, h1b, als1, ald1,
                                                    b1, W2, a_src2, a_dst2, h2b, als2, ald2);
    gather2_kernel<<<N_NODES / 4, 256, 0, stream>>>(row_ptr, cnt, csr, h2b, als2, ald2, b2, out);
}